// Round 11
// baseline (69.000 us; speedup 1.0000x reference)
//
#include <hip/hip_runtime.h>
#include <hip/hip_bf16.h>
#include <hip/hip_cooperative_groups.h>

namespace cg = cooperative_groups;

#define TT 2048
#define CC 1024
#define HH 16
#define DD 64
#define FM 64
#define NCH 32
#define CL 64
#define N_QKV 3072
#define EPSV 1e-6f

// fp32 workspace region (float units)
#define OFF_KS  0u          // Ksum fp32 [16][32][64m]
#define OFF_Z   32768u      // z fp32 [16][32][64m]
#define OFF_U16 65536u      // bf16 region start (float units)
// bf16 region offsets (ushort units)
#define U_KVT 0u            // KV^T bf16 [16][32][64d][64m]
#define U_PROJT 2097152u    // projT bf16 [16][64m][64d]
#define U_VT  6291456u      // v^T bf16 [16][64][2048]
#define U_QP  8388608u      // q' bf16 [16][2048][64m]
#define U_KP  10485760u     // k' bf16 [16][2048][64m]
#define U_ST  12582912u     // S^T bf16 [16][32][64d][64m]
#define U_XBF 14680064u     // x bf16 (later aliased as attnb)
#define U_WQT 16777216u     // w_qkv^T bf16 [3072][1024]
#define U_WOT 19922944u     // w_out^T bf16 [1024][1024]

typedef __attribute__((ext_vector_type(8))) short bf16x8;
typedef __attribute__((ext_vector_type(4))) float f32x4;
typedef __attribute__((ext_vector_type(4))) unsigned short u16x4;

__device__ __forceinline__ unsigned short f2bf(float f) {
  unsigned int u = __float_as_uint(f);
  u = (u + 0x7fffu + ((u >> 16) & 1u)) >> 16;
  return (unsigned short)u;
}
__device__ __forceinline__ float bf2f(unsigned short b) {
  return __uint_as_float(((unsigned)b) << 16);
}

__device__ __forceinline__ void gload16(const void* g, void* l) {
  __builtin_amdgcn_global_load_lds(
      (const __attribute__((address_space(1))) unsigned int*)g,
      (__attribute__((address_space(3))) unsigned int*)l, 16, 0, 0);
}

// stage a 64-row x 64-ushort (8KB) tile into LDS, XOR-swizzled (chunk^=row&7)
__device__ __forceinline__ void stage_tile64(const unsigned short* g, unsigned rowstride,
                                             unsigned short* lds, int w, int lane) {
  const int l8 = lane >> 3, l7 = lane & 7;
  const int kcg = (l7 ^ l8) * 8;
#pragma unroll
  for (int jj = 0; jj < 2; ++jj) {
    const int inst = w * 2 + jj;
    const int row = inst * 8 + l8;
    gload16(&g[(unsigned)row * rowstride + kcg], &lds[inst * 512]);
  }
}

// read an 8-element bf16 fragment from a swizzled 64x64 LDS tile
__device__ __forceinline__ bf16x8 frag64(const unsigned short* lds, int r, int kchunk) {
  const int slot = kchunk ^ (r & 7);
  return *reinterpret_cast<const bf16x8*>(&lds[r * 64 + slot * 8]);
}

// ======================= phase bodies (shared device code) ==================

__device__ __forceinline__ void transpose64_dev(const float* __restrict__ src,
                                                unsigned short* __restrict__ dst,
                                                int K, int N, int k0, int n0,
                                                float (*T)[68], int tid) {
#pragma unroll
  for (int it = 0; it < 4; ++it) {
    int f = tid + it * 256;
    int r = f >> 4, c4 = (f & 15) * 4;
    float4 v = *reinterpret_cast<const float4*>(&src[(unsigned)(k0 + r) * N + n0 + c4]);
    T[r][c4 + 0] = v.x; T[r][c4 + 1] = v.y;
    T[r][c4 + 2] = v.z; T[r][c4 + 3] = v.w;
  }
  __syncthreads();
#pragma unroll
  for (int it = 0; it < 4; ++it) {
    int f = tid + it * 256;
    int nl = f >> 4, kq = (f & 15) * 4;
    u16x4 o;
#pragma unroll
    for (int j = 0; j < 4; ++j) o[j] = f2bf(T[kq + j][nl]);
    *reinterpret_cast<u16x4*>(&dst[(unsigned)(n0 + nl) * K + k0 + kq]) = o;
  }
}

__device__ __forceinline__ void prep_item(int b, const float* __restrict__ x,
                                          const float* __restrict__ wq,
                                          const float* __restrict__ wo,
                                          const float* __restrict__ proj,
                                          unsigned short* __restrict__ xbf,
                                          unsigned short* __restrict__ wqT,
                                          unsigned short* __restrict__ woT,
                                          unsigned short* __restrict__ projT,
                                          float (*T)[68]) {
  const int tid = threadIdx.x;
  if (b < 2048) {  // x f32 -> bf16
    unsigned i = (unsigned)b * 1024u + (unsigned)tid * 4u;
    float4 v = *reinterpret_cast<const float4*>(&x[i]);
    u16x4 o;
    o[0] = f2bf(v.x); o[1] = f2bf(v.y); o[2] = f2bf(v.z); o[3] = f2bf(v.w);
    *reinterpret_cast<u16x4*>(&xbf[i]) = o;
  } else if (b < 2816) {
    int bb = b - 2048;
    transpose64_dev(wq, wqT, CC, N_QKV, (bb / 48) * 64, (bb % 48) * 64, T, tid);
  } else if (b < 3072) {
    int bb = b - 2816;
    transpose64_dev(wo, woT, CC, CC, (bb / 16) * 64, (bb % 16) * 64, T, tid);
  } else {
    int bb = b - 3072;
    transpose64_dev(proj + (unsigned)bb * 4096u, projT + (unsigned)bb * 4096u,
                    64, 64, 0, 0, T, tid);
  }
}

// qkv GEMM (64x128 tile) + fused feature map. LDSU needs 12288 ushorts.
__device__ __forceinline__ void qkv_body(int lin, const unsigned short* __restrict__ Xbf,
                                         const unsigned short* __restrict__ WqT,
                                         const float* __restrict__ bias,
                                         const unsigned short* __restrict__ projT,
                                         unsigned short* __restrict__ qp,
                                         unsigned short* __restrict__ kp,
                                         unsigned short* __restrict__ vt,
                                         unsigned short* LDSU) {
  unsigned short* As = LDSU;
  unsigned short* Bs = LDSU + 4096;
  const int tid = threadIdx.x, lane = tid & 63, w = tid >> 6;
  const int wm = w >> 1, wn = w & 1;   // 2M x 2N warp layout (32 x 64 per warp)
  // XCD-aware bijective swizzle: nwg = 768, 768%8==0, cpx=96
  int swz = (lin & 7) * 96 + (lin >> 3);
  const int bx = swz % 24, by = swz / 24;
  const int m0b = by * 64, n0b = bx * 128;
  const int l8 = lane >> 3, l7 = lane & 7;
  const int kcg = (l7 ^ l8) * 8;
  f32x4 acc[2][4] = {};
  for (int k0 = 0; k0 < CC; k0 += 64) {
    if (k0) __syncthreads();
#pragma unroll
    for (int jj = 0; jj < 2; ++jj) {   // A: 64x64
      const int inst = w * 2 + jj;
      const int row = inst * 8 + l8;
      gload16(&Xbf[(unsigned)(m0b + row) * CC + k0 + kcg], &As[inst * 512]);
    }
#pragma unroll
    for (int jj = 0; jj < 4; ++jj) {   // B: 128x64
      const int inst = w * 4 + jj;
      const int row = inst * 8 + l8;
      gload16(&WqT[(unsigned)(n0b + row) * CC + k0 + kcg], &Bs[inst * 512]);
    }
    __syncthreads();
#pragma unroll
    for (int kk = 0; kk < 2; ++kk) {
      bf16x8 af[2], bg[4];
#pragma unroll
      for (int i = 0; i < 2; ++i) {
        const int r = wm * 32 + i * 16 + (lane & 15);
        const int slot = (kk * 4 + (lane >> 4)) ^ (r & 7);
        af[i] = *reinterpret_cast<const bf16x8*>(&As[r * 64 + slot * 8]);
      }
#pragma unroll
      for (int j = 0; j < 4; ++j) {
        const int r = wn * 64 + j * 16 + (lane & 15);
        const int slot = (kk * 4 + (lane >> 4)) ^ (r & 7);
        bg[j] = *reinterpret_cast<const bf16x8*>(&Bs[r * 64 + slot * 8]);
      }
#pragma unroll
      for (int i = 0; i < 2; ++i)
#pragma unroll
        for (int j = 0; j < 4; ++j)
          acc[i][j] = __builtin_amdgcn_mfma_f32_16x16x32_bf16(af[i], bg[j],
                                                              acc[i][j], 0, 0, 0);
    }
  }
  const int n0w = n0b + wn * 64;       // one (sel,h) per warp
  const int sel = n0w >> 10;
  const int h = (n0w & 1023) >> 6;
  const int t0w = m0b + wm * 32;
  float bvj[4];
#pragma unroll
  for (int j = 0; j < 4; ++j) bvj[j] = bias[n0w + j * 16 + (lane & 15)];
  __syncthreads();  // all MFMA reads of LDSU done
  // stage warp's 32t x 64d tile (+bias, bf16) into private quadrant, swizzled
  unsigned short* myT = LDSU + w * 2048;
#pragma unroll
  for (int i = 0; i < 2; ++i)
#pragma unroll
    for (int j = 0; j < 4; ++j) {
      const int d = j * 16 + (lane & 15);
#pragma unroll
      for (int r = 0; r < 4; ++r) {
        const int t = i * 16 + (lane >> 4) * 4 + r;
        myT[t * 64 + (((d >> 3) ^ (t & 7)) << 3) + (d & 7)] = f2bf(acc[i][j][r] + bvj[j]);
      }
    }
  if (sel == 2) {
    // vT [h][d][t]: per lane 4x bf16x8 along t (64B-line writes)
#pragma unroll
    for (int q = 0; q < 4; ++q) {
      const int cid = q * 64 + lane;
      const int d = cid >> 2, tc = cid & 3;
      bf16x8 o;
#pragma unroll
      for (int e = 0; e < 8; ++e) {
        const int t = tc * 8 + e;
        o[e] = (short)myT[t * 64 + (((d >> 3) ^ (t & 7)) << 3) + (d & 7)];
      }
      *reinterpret_cast<bf16x8*>(&vt[((unsigned)h * 64 + d) * TT + t0w + tc * 8]) = o;
    }
  } else {
    // fused feature map: p'[t][m] = relu(sum_d tile[t][d] projT[h][m][d]) / 8
    const unsigned short* pjt = projT + (unsigned)h * 4096u;
    bf16x8 aq[2][2], bp[4][2];
#pragma unroll
    for (int jm = 0; jm < 4; ++jm)
#pragma unroll
      for (int kk = 0; kk < 2; ++kk)
        bp[jm][kk] = *reinterpret_cast<const bf16x8*>(
            &pjt[(unsigned)(jm * 16 + (lane & 15)) * 64 + kk * 32 + (lane >> 4) * 8]);
#pragma unroll
    for (int i = 0; i < 2; ++i)
#pragma unroll
      for (int kk = 0; kk < 2; ++kk)
        aq[i][kk] = frag64(myT, i * 16 + (lane & 15), kk * 4 + (lane >> 4));
    f32x4 accp[2][4] = {};
#pragma unroll
    for (int i = 0; i < 2; ++i)
#pragma unroll
      for (int jm = 0; jm < 4; ++jm)
#pragma unroll
        for (int kk = 0; kk < 2; ++kk)
          accp[i][jm] = __builtin_amdgcn_mfma_f32_16x16x32_bf16(aq[i][kk], bp[jm][kk],
                                                                accp[i][jm], 0, 0, 0);
    // relu/8 + restage p' into myT as [t][m] swizzled (warp-private, in-order DS)
#pragma unroll
    for (int i = 0; i < 2; ++i)
#pragma unroll
      for (int jm = 0; jm < 4; ++jm) {
        const int m = jm * 16 + (lane & 15);
#pragma unroll
        for (int r = 0; r < 4; ++r) {
          const int t = i * 16 + (lane >> 4) * 4 + r;
          float v = accp[i][jm][r];
          v = (v > 0.f ? v : 0.f) * 0.125f;
          myT[t * 64 + (((m >> 3) ^ (t & 7)) << 3) + (m & 7)] = f2bf(v);
        }
      }
    // coalesced store: q'/k' [h][t][m], 1KB per store instruction
    unsigned short* dst0 = (sel ? kp : qp) + ((unsigned)h * TT + (unsigned)t0w) * 64u;
#pragma unroll
    for (int q = 0; q < 4; ++q) {
      const int cid = q * 64 + lane;
      const int t = cid >> 3, mc = cid & 7;
      bf16x8 o = *reinterpret_cast<const bf16x8*>(&myT[t * 64 + ((mc ^ (t & 7)) << 3)]);
      *reinterpret_cast<bf16x8*>(&dst0[(unsigned)cid * 8]) = o;
    }
  }
}

// per-chunk KV^T[d][m] + Ksum. LDSU needs 8192 ushorts.
__device__ __forceinline__ void chunkkv_body(int c, int h,
                                             const unsigned short* __restrict__ kp,
                                             const unsigned short* __restrict__ vt,
                                             unsigned short* __restrict__ kvt,
                                             float* __restrict__ ksum,
                                             unsigned short* LDSU) {
  unsigned short* Xs = LDSU;
  unsigned short* VTs = LDSU + 4096;
  const int tid = threadIdx.x, lane = tid & 63, w = tid >> 6;
  stage_tile64(kp + ((unsigned)h * TT + c * 64) * 64, 64, Xs, w, lane);
  stage_tile64(vt + (unsigned)h * 64 * TT + (unsigned)c * 64, TT, VTs, w, lane);
  __syncthreads();
  const int m = w * 16 + (lane & 15);
  bf16x8 afm[2];
  float ks = 0.f;
#pragma unroll
  for (int kk = 0; kk < 2; ++kk)
#pragma unroll
    for (int e = 0; e < 8; ++e) {
      const int t = kk * 32 + (lane >> 4) * 8 + e;
      unsigned short u = Xs[t * 64 + (((m >> 3) ^ (t & 7)) << 3) + (m & 7)];
      afm[kk][e] = (short)u;
      ks += bf2f(u);
    }
  ks += __shfl_xor(ks, 16, 64);
  ks += __shfl_xor(ks, 32, 64);
  if (lane < 16) ksum[((unsigned)h * NCH + c) * 64u + m] = ks;
  f32x4 acckv[4] = {};
#pragma unroll
  for (int j = 0; j < 4; ++j)
#pragma unroll
    for (int kk = 0; kk < 2; ++kk)
      acckv[j] = __builtin_amdgcn_mfma_f32_16x16x32_bf16(
          afm[kk], frag64(VTs, j * 16 + (lane & 15), kk * 4 + (lane >> 4)), acckv[j], 0, 0, 0);
  unsigned short* dkv = kvt + ((unsigned)h * NCH + c) * 4096u;
#pragma unroll
  for (int j = 0; j < 4; ++j) {
    const int d = j * 16 + (lane & 15);
    const int mq = w * 16 + (lane >> 4) * 4;
    u16x4 o;
#pragma unroll
    for (int r = 0; r < 4; ++r) o[r] = f2bf(acckv[j][r]);
    *reinterpret_cast<u16x4*>(&dkv[(unsigned)d * 64 + mq]) = o;
  }
}

__device__ __forceinline__ void prefix_body(int bxp, int h,
                                            const unsigned short* __restrict__ kvt,
                                            const float* __restrict__ ksum,
                                            unsigned short* __restrict__ st,
                                            float* __restrict__ z) {
  const unsigned e = (unsigned)bxp * 256u + threadIdx.x;
  float run = 0.f;
#pragma unroll
  for (int c = 0; c < NCH; ++c) {
    const unsigned idx = ((unsigned)h * NCH + c) * 4096u + e;
    st[idx] = f2bf(run);
    run += bf2f(kvt[idx]);
  }
  if (bxp == 0 && threadIdx.x < 64) {
    float zr = 0.f;
#pragma unroll
    for (int c = 0; c < NCH; ++c) {
      const unsigned idx = ((unsigned)h * NCH + c) * 64u + threadIdx.x;
      z[idx] = zr;
      zr += ksum[idx];
    }
  }
}

// intra-chunk attention. LDSU needs 16640 ushorts (4 tiles + zsm/nsm).
__device__ __forceinline__ void attn_body(int c, int h,
                                          const unsigned short* __restrict__ qp,
                                          const unsigned short* __restrict__ kp,
                                          const unsigned short* __restrict__ vt,
                                          const unsigned short* __restrict__ st,
                                          const float* __restrict__ z,
                                          unsigned short* __restrict__ attnb,
                                          unsigned short* LDSU) {
  unsigned short* QPs = LDSU;           // reused as ctx bf16 at epilogue
  unsigned short* KPs = LDSU + 4096;    // reused as A^bf16 after phase A
  unsigned short* VTs = LDSU + 8192;
  unsigned short* STs = LDSU + 12288;
  float* zsm = (float*)(LDSU + 16384);
  float* nsm = zsm + 64;
  const int tid = threadIdx.x, lane = tid & 63, w = tid >> 6;
  stage_tile64(qp + ((unsigned)h * TT + c * 64) * 64, 64, QPs, w, lane);
  stage_tile64(kp + ((unsigned)h * TT + c * 64) * 64, 64, KPs, w, lane);
  stage_tile64(vt + (unsigned)h * 64 * TT + (unsigned)c * 64, TT, VTs, w, lane);
  stage_tile64(st + ((unsigned)h * NCH + c) * 4096u, 64, STs, w, lane);
  if (tid < 64) zsm[tid] = z[((unsigned)h * NCH + c) * 64u + tid];
  __syncthreads();
  const int tr = w * 16 + (lane & 15);
  bf16x8 afq[2];
#pragma unroll
  for (int kk = 0; kk < 2; ++kk) afq[kk] = frag64(QPs, tr, kk * 4 + (lane >> 4));
  f32x4 accA[4] = {};
#pragma unroll
  for (int j = 0; j < 4; ++j)
#pragma unroll
    for (int kk = 0; kk < 2; ++kk)
      accA[j] = __builtin_amdgcn_mfma_f32_16x16x32_bf16(
          afq[kk], frag64(KPs, j * 16 + (lane & 15), kk * 4 + (lane >> 4)), accA[j], 0, 0, 0);
  float rs[4] = {0.f, 0.f, 0.f, 0.f};
#pragma unroll
  for (int j = 0; j < 4; ++j) {
    const int s = j * 16 + (lane & 15);
#pragma unroll
    for (int r = 0; r < 4; ++r) {
      const int t = w * 16 + (lane >> 4) * 4 + r;
      float v = (s <= t) ? accA[j][r] : 0.f;
      accA[j][r] = v;
      rs[r] += v;
    }
  }
#pragma unroll
  for (int r = 0; r < 4; ++r)
#pragma unroll
    for (int off = 1; off < 16; off <<= 1) rs[r] += __shfl_xor(rs[r], off, 64);
  __syncthreads();
  if ((lane & 15) == 0) {
#pragma unroll
    for (int r = 0; r < 4; ++r) nsm[w * 16 + (lane >> 4) * 4 + r] = rs[r];
  }
#pragma unroll
  for (int j = 0; j < 4; ++j) {
    const int s = j * 16 + (lane & 15);
#pragma unroll
    for (int r = 0; r < 4; ++r) {
      const int t = w * 16 + (lane >> 4) * 4 + r;
      KPs[t * 64 + (((s >> 3) ^ (t & 7)) * 8) + (s & 7)] = f2bf(accA[j][r]);
    }
  }
  __syncthreads();
  {
    const int t = tid >> 2, part = tid & 3;
    float qz = 0.f;
#pragma unroll
    for (int mm = 0; mm < 16; ++mm) {
      const int m = part * 16 + mm;
      qz += bf2f(QPs[t * 64 + (((m >> 3) ^ (t & 7)) * 8) + (m & 7)]) * zsm[m];
    }
    qz += __shfl_xor(qz, 1, 64);
    qz += __shfl_xor(qz, 2, 64);
    if (part == 0) nsm[t] += qz + EPSV;
  }
  bf16x8 afa[2];
#pragma unroll
  for (int kk = 0; kk < 2; ++kk) afa[kk] = frag64(KPs, tr, kk * 4 + (lane >> 4));
  f32x4 acc[4] = {};
#pragma unroll
  for (int j = 0; j < 4; ++j) {
    const int br = j * 16 + (lane & 15);
#pragma unroll
    for (int kk = 0; kk < 2; ++kk) {
      acc[j] = __builtin_amdgcn_mfma_f32_16x16x32_bf16(
          afa[kk], frag64(VTs, br, kk * 4 + (lane >> 4)), acc[j], 0, 0, 0);
      acc[j] = __builtin_amdgcn_mfma_f32_16x16x32_bf16(
          afq[kk], frag64(STs, br, kk * 4 + (lane >> 4)), acc[j], 0, 0, 0);
    }
  }
  __syncthreads();  // nsm finalized; QPs dead -> reuse for ctx staging
#pragma unroll
  for (int j = 0; j < 4; ++j) {
    const int d = j * 16 + (lane & 15);
#pragma unroll
    for (int r = 0; r < 4; ++r) {
      const int t = w * 16 + (lane >> 4) * 4 + r;
      QPs[t * 64 + (((d >> 3) ^ (t & 7)) << 3) + (d & 7)] = f2bf(acc[j][r] / nsm[t]);
    }
  }
  __syncthreads();
  unsigned short* dstA = attnb + (unsigned)(c * 64) * CC + (unsigned)h * 64;
#pragma unroll
  for (int q = 0; q < 2; ++q) {
    const int cid = q * 256 + tid;
    const int t = cid >> 3, dc = cid & 7;
    bf16x8 o = *reinterpret_cast<const bf16x8*>(&QPs[t * 64 + ((dc ^ (t & 7)) << 3)]);
    *reinterpret_cast<bf16x8*>(&dstA[(unsigned)t * CC + dc * 8]) = o;
  }
}

// out GEMM (64x64 tile). LDSU needs 8192 ushorts.
__device__ __forceinline__ void out_body(int lin, const unsigned short* __restrict__ Abf,
                                         const unsigned short* __restrict__ WoT,
                                         const float* __restrict__ bias,
                                         float* __restrict__ out,
                                         unsigned short* LDSU) {
  unsigned short* As = LDSU;
  unsigned short* Bs = LDSU + 4096;
  const int tid = threadIdx.x, lane = tid & 63, w = tid >> 6;
  const int wm = w >> 1, wn = w & 1;   // 2M x 2N, 32x32 per warp
  int swz = (lin & 7) * 64 + (lin >> 3);
  const int bx = swz & 15, by = swz >> 4;
  const int m0 = by * 64, n0 = bx * 64;
  const int l8 = lane >> 3, l7 = lane & 7;
  const int kcg = (l7 ^ l8) * 8;
  f32x4 acc[2][2] = {};
  for (int k0 = 0; k0 < CC; k0 += 64) {
    if (k0) __syncthreads();
#pragma unroll
    for (int jj = 0; jj < 2; ++jj) {
      const int inst = w * 2 + jj;
      const int row = inst * 8 + l8;
      gload16(&Abf[(unsigned)(m0 + row) * CC + k0 + kcg], &As[inst * 512]);
      gload16(&WoT[(unsigned)(n0 + row) * CC + k0 + kcg], &Bs[inst * 512]);
    }
    __syncthreads();
#pragma unroll
    for (int kk = 0; kk < 2; ++kk) {
      bf16x8 af[2], bg[2];
#pragma unroll
      for (int i = 0; i < 2; ++i) {
        const int r = wm * 32 + i * 16 + (lane & 15);
        const int slot = (kk * 4 + (lane >> 4)) ^ (r & 7);
        af[i] = *reinterpret_cast<const bf16x8*>(&As[r * 64 + slot * 8]);
      }
#pragma unroll
      for (int j = 0; j < 2; ++j) {
        const int r = wn * 32 + j * 16 + (lane & 15);
        const int slot = (kk * 4 + (lane >> 4)) ^ (r & 7);
        bg[j] = *reinterpret_cast<const bf16x8*>(&Bs[r * 64 + slot * 8]);
      }
#pragma unroll
      for (int i = 0; i < 2; ++i)
#pragma unroll
        for (int j = 0; j < 2; ++j)
          acc[i][j] = __builtin_amdgcn_mfma_f32_16x16x32_bf16(af[i], bg[j],
                                                              acc[i][j], 0, 0, 0);
    }
  }
#pragma unroll
  for (int i = 0; i < 2; ++i) {
#pragma unroll
    for (int j = 0; j < 2; ++j) {
      const int n = n0 + wn * 32 + j * 16 + (lane & 15);
      const float bv = bias[n];
#pragma unroll
      for (int r = 0; r < 4; ++r) {
        const int m = m0 + wm * 32 + i * 16 + (lane >> 4) * 4 + r;
        out[(unsigned)m * CC + n] = acc[i][j][r] + bv;
      }
    }
  }
}

// ======================= fallback per-phase kernels =========================

__global__ __launch_bounds__(256) void k_prep(const float* x, const float* wq,
                                              const float* wo, const float* proj,
                                              unsigned short* xbf, unsigned short* wqT,
                                              unsigned short* woT, unsigned short* projT) {
  __shared__ float T[64][68];
  prep_item(blockIdx.x, x, wq, wo, proj, xbf, wqT, woT, projT, T);
}

__global__ __launch_bounds__(256) void k_qkv_mfma(const unsigned short* Xbf,
                                                  const unsigned short* WqT,
                                                  const float* bias,
                                                  const unsigned short* projT,
                                                  unsigned short* qp, unsigned short* kp,
                                                  unsigned short* vt) {
  __shared__ unsigned short LDSU[12288];
  qkv_body(blockIdx.y * 24 + blockIdx.x, Xbf, WqT, bias, projT, qp, kp, vt, LDSU);
}

__global__ __launch_bounds__(256) void k_chunkkv(const unsigned short* kp,
                                                 const unsigned short* vt,
                                                 unsigned short* kvt, float* ksum) {
  __shared__ unsigned short LDSU[8192];
  chunkkv_body(blockIdx.x, blockIdx.y, kp, vt, kvt, ksum, LDSU);
}

__global__ __launch_bounds__(256) void k_prefix(const unsigned short* kvt,
                                                const float* ksum,
                                                unsigned short* st, float* z) {
  prefix_body(blockIdx.x, blockIdx.y, kvt, ksum, st, z);
}

__global__ __launch_bounds__(256) void k_attn(const unsigned short* qp,
                                              const unsigned short* kp,
                                              const unsigned short* vt,
                                              const unsigned short* st,
                                              const float* z, unsigned short* attnb) {
  __shared__ unsigned short LDSU[16640];
  attn_body(blockIdx.x, blockIdx.y, qp, kp, vt, st, z, attnb, LDSU);
}

__global__ __launch_bounds__(256) void k_out_mfma(const unsigned short* Abf,
                                                  const unsigned short* WoT,
                                                  const float* bias, float* out) {
  __shared__ unsigned short LDSU[8192];
  out_body(blockIdx.y * 16 + blockIdx.x, Abf, WoT, bias, out, LDSU);
}

// ======================= cooperative mega-kernel ============================

__global__ __launch_bounds__(256, 3) void k_mega(const float* x, const float* wq,
                                                 const float* wo, const float* proj,
                                                 const float* bq, const float* bo,
                                                 unsigned short* xbf, unsigned short* wqT,
                                                 unsigned short* woT, unsigned short* projT,
                                                 unsigned short* qp, unsigned short* kp,
                                                 unsigned short* vt, unsigned short* kvt,
                                                 float* ksum, unsigned short* st, float* zf,
                                                 unsigned short* attnb, float* out) {
  __shared__ __align__(16) unsigned short LDSU[16640];  // 33.3 KB union of all phases
  cg::grid_group grid = cg::this_grid();
  const int blk = blockIdx.x;  // grid = 768
  // phase 0: prep (grid-stride over 3088 items)
  for (int b = blk; b < 3088; b += 768) {
    prep_item(b, x, wq, wo, proj, xbf, wqT, woT, projT, (float(*)[68])LDSU);
    __syncthreads();  // protect LDS reuse across iterations (uniform per block)
  }
  grid.sync();
  // phase 1: qkv GEMM + feature map (all 768 blocks)
  qkv_body(blk, xbf, wqT, bq, projT, qp, kp, vt, LDSU);
  grid.sync();
  // phase 2: per-chunk KV (512 blocks)
  if (blk < 512) chunkkv_body(blk & 31, blk >> 5, kp, vt, kvt, ksum, LDSU);
  grid.sync();
  // phase 3: chunk prefix scan (256 blocks)
  if (blk < 256) prefix_body(blk & 15, blk >> 4, kvt, ksum, st, zf);
  grid.sync();
  // phase 4: intra-chunk attention (512 blocks)
  if (blk < 512) attn_body(blk & 31, blk >> 5, qp, kp, vt, st, zf, attnb, LDSU);
  grid.sync();
  // phase 5: output GEMM (512 blocks)
  if (blk < 512) out_body(blk, attnb, woT, bo, out, LDSU);
}

extern "C" void kernel_launch(void* const* d_in, const int* in_sizes, int n_in,
                              void* d_out, int out_size, void* d_ws, size_t ws_size,
                              hipStream_t stream) {
  const float* x = (const float*)d_in[0];
  const float* w_qkv = (const float*)d_in[1];
  const float* b_qkv = (const float*)d_in[2];
  const float* w_out = (const float*)d_in[3];
  const float* b_out = (const float*)d_in[4];
  const float* proj = (const float*)d_in[5];
  float* ws = (float*)d_ws;
  float* out = (float*)d_out;
  float* ksum = ws + OFF_KS;
  float* zf = ws + OFF_Z;
  unsigned short* ub = (unsigned short*)(ws + OFF_U16);
  unsigned short* kvt = ub + U_KVT;
  unsigned short* projT = ub + U_PROJT;
  unsigned short* vt = ub + U_VT;
  unsigned short* qp = ub + U_QP;
  unsigned short* kp = ub + U_KP;
  unsigned short* st = ub + U_ST;
  unsigned short* xbf = ub + U_XBF;
  unsigned short* wqT = ub + U_WQT;
  unsigned short* woT = ub + U_WOT;
  unsigned short* attnb = xbf;  // alias: x_bf16 dead after qkv phase

  int dev = 0;
  hipGetDevice(&dev);
  int coop = 0;
  hipDeviceGetAttribute(&coop, hipDeviceAttributeCooperativeLaunch, dev);
  int nb = 0;
  hipOccupancyMaxActiveBlocksPerMultiprocessor(&nb, k_mega, 256, 0);

  if (coop && nb >= 3) {
    void* args[] = {(void*)&x, (void*)&w_qkv, (void*)&w_out, (void*)&proj,
                    (void*)&b_qkv, (void*)&b_out,
                    (void*)&xbf, (void*)&wqT, (void*)&woT, (void*)&projT,
                    (void*)&qp, (void*)&kp, (void*)&vt, (void*)&kvt,
                    (void*)&ksum, (void*)&st, (void*)&zf, (void*)&attnb, (void*)&out};
    hipLaunchCooperativeKernel((void*)k_mega, dim3(768), dim3(256), args, 0, stream);
  } else {
    dim3 blk(256, 1, 1);
    k_prep<<<dim3(3088), blk, 0, stream>>>(x, w_qkv, w_out, proj, xbf, wqT, woT, projT);
    k_qkv_mfma<<<dim3(N_QKV / 128, TT / 64), blk, 0, stream>>>(xbf, wqT, b_qkv, projT,
                                                               qp, kp, vt);
    k_chunkkv<<<dim3(NCH, HH), blk, 0, stream>>>(kp, vt, kvt, ksum);
    k_prefix<<<dim3(16, HH), blk, 0, stream>>>(kvt, ksum, st, zf);
    k_attn<<<dim3(NCH, HH), blk, 0, stream>>>(qp, kp, vt, st, zf, attnb);
    k_out_mfma<<<dim3(CC / 64, TT / 64), blk, 0, stream>>>(attnb, woT, b_out, out);
  }
}